// Round 3
// baseline (1131.671 us; speedup 1.0000x reference)
//
#include <hip/hip_runtime.h>
#include <hip/hip_fp16.h>
#include <math.h>

#define BATCH 8
#define H 480
#define W 640
#define HW (H * W)

#define TW 64                 // tile width  (== wave lanes)
#define TH 48                 // tile height
#define NBX (W / TW)          // 10
#define NBY (H / TH)          // 10
#define NBLK (NBX * NBY * BATCH)  // 800 blocks <= 1024 co-residency bound
#define RXs (TW + 2)          // 66 region cols
#define RYs (TH + 2)          // 50 region rows
#define RPX (TH / 4)          // 12 rows per thread (4 waves x 64 lanes)
#define NSTEP 16

// ring layout per block per parity (256 u32):
// [0,64) top row, [64,128) bottom row, [128,176) left col, [176,224) right col
#define RING_STRIDE 256

__device__ __forceinline__ float2 up2(unsigned u) {
    __half2 h = *reinterpret_cast<const __half2*>(&u);
    return __half22float2(h);
}
__device__ __forceinline__ unsigned pk2(float a, float b) {
    unsigned lo = __half_as_ushort(__float2half_rn(a));
    unsigned hi = __half_as_ushort(__float2half_rn(b));
    return lo | (hi << 16);
}
__device__ __forceinline__ void ring_st(unsigned* p, float v) {
    __hip_atomic_store(p, __float_as_uint(v), __ATOMIC_RELAXED, __HIP_MEMORY_SCOPE_AGENT);
}

__global__ __launch_bounds__(256, 4) void prop_persistent(
    const float* __restrict__ guided,   // (B,9,H,W)
    const float* __restrict__ x,        // (B,1,H,W)
    const float* __restrict__ sparse,   // (B,1,H,W)
    float* __restrict__ out,            // (B,1,H,W)
    unsigned* __restrict__ flags,       // NBLK, zeroed per launch
    unsigned* __restrict__ rings)       // 2 * NBLK * RING_STRIDE
{
    __shared__ float xs[RYs * RXs];

    const int bx = blockIdx.x, by = blockIdx.y, b = blockIdx.z;
    const int blk = (b * NBY + by) * NBX + bx;
    const int tid = threadIdx.x;
    const int lane = tid & 63;          // tile column
    const int wv = tid >> 6;            // wave id -> row strip
    const int bx0 = bx * TW, by0 = by * TH;

    // ---- load x0 region (with 1-px halo, zeros outside image) into LDS ----
    for (int j = tid; j < RYs * RXs; j += 256) {
        const int R = j / RXs, C = j % RXs;
        const int gy = by0 - 1 + R, gx = bx0 - 1 + C;
        float v = 0.0f;
        if (gy >= 0 && gy < H && gx >= 0 && gx < W)
            v = x[(size_t)b * HW + (size_t)gy * W + gx];
        xs[j] = v;
    }
    __syncthreads();

    // ---- per-own-pixel softmax + mask fold, packed fp16 in registers ----
    uint4 wq[RPX];
    unsigned wb[RPX];
    {
        const int gx = bx0 + lane;
#pragma unroll
        for (int r = 0; r < RPX; ++r) {
            const int ty = wv * RPX + r;
            const int gy = by0 + ty;
            const size_t rowoff = (size_t)gy * W + gx;
            float g[9];
            float m = -INFINITY;
#pragma unroll
            for (int k = 0; k < 9; ++k) {
                g[k] = guided[((size_t)(b * 9 + k)) * HW + rowoff];
                m = fmaxf(m, g[k]);
            }
            float s = 0.0f;
#pragma unroll
            for (int k = 0; k < 9; ++k) { g[k] = __expf(g[k] - m); s += g[k]; }
            const float sv = sparse[(size_t)b * HW + rowoff];
            const float mask = (sv > 0.0f) ? 1.0f : ((sv < 0.0f) ? -1.0f : 0.0f);
            const float scale = (1.0f - mask) / s;
            const float x0 = xs[(1 + ty) * RXs + (lane + 1)];
            wq[r].x = pk2(g[0] * scale, g[1] * scale);
            wq[r].y = pk2(g[2] * scale, g[3] * scale);
            wq[r].z = pk2(g[4] * scale, g[5] * scale);
            wq[r].w = pk2(g[6] * scale, g[7] * scale);
            wb[r]   = pk2(g[8] * scale, mask * x0);
        }
    }

    // ---- neighbor bookkeeping ----
    int spin_nb = -1;                   // threads 0..7: one neighbor each
    if (tid < 8) {
        const int dxs[8] = {-1, 0, 1, -1, 1, -1, 0, 1};
        const int dys[8] = {-1, -1, -1, 0, 0, 1, 1, 1};
        const int nx = bx + dxs[tid], ny = by + dys[tid];
        if (nx >= 0 && nx < NBX && ny >= 0 && ny < NBY)
            spin_nb = (b * NBY + ny) * NBX + nx;
    }
    int h_nb = -1, h_off = 0, h_dst = 0;  // threads 0..227: one halo px each
    if (tid < 228) {
        int ddx = 0, ddy = 0;
        if (tid < 66) {                 // top halo row (region row 0)
            const int i = tid; h_dst = i;
            if (i == 0)       { ddx = -1; ddy = -1; h_off = 64 + 63; }
            else if (i == 65) { ddx =  1; ddy = -1; h_off = 64 + 0; }
            else              { ddx =  0; ddy = -1; h_off = 64 + (i - 1); }
        } else if (tid < 132) {         // bottom halo row (region row RYs-1)
            const int i = tid - 66; h_dst = (RYs - 1) * RXs + i;
            if (i == 0)       { ddx = -1; ddy = 1; h_off = 63; }
            else if (i == 65) { ddx =  1; ddy = 1; h_off = 0; }
            else              { ddx =  0; ddy = 1; h_off = i - 1; }
        } else if (tid < 180) {         // left halo col
            const int rr = tid - 132; h_dst = (1 + rr) * RXs;
            ddx = -1; ddy = 0; h_off = 176 + rr;       // their right col
        } else {                        // right halo col
            const int rr = tid - 180; h_dst = (1 + rr) * RXs + (RXs - 1);
            ddx = 1; ddy = 0; h_off = 128 + rr;        // their left col
        }
        const int nx = bx + ddx, ny = by + ddy;
        if (nx >= 0 && nx < NBX && ny >= 0 && ny < NBY)
            h_nb = (b * NBY + ny) * NBX + nx;
    }

    // ---- 16 Jacobi steps ----
    for (int t = 1; t <= NSTEP; ++t) {
        if (t > 1) {
            if (tid < 8 && spin_nb >= 0) {
                const unsigned want = (unsigned)(t - 1);
                long guard = 0;
                while (__hip_atomic_load(&flags[spin_nb], __ATOMIC_ACQUIRE,
                                         __HIP_MEMORY_SCOPE_AGENT) < want) {
                    __builtin_amdgcn_s_sleep(2);
                    if (++guard > (1L << 31)) break;   // safety valve
                }
            }
            __syncthreads();
            if (h_nb >= 0) {
                const size_t off =
                    ((size_t)((t - 1) & 1) * NBLK + (size_t)h_nb) * RING_STRIDE + h_off;
                const unsigned u = __hip_atomic_load(&rings[off], __ATOMIC_RELAXED,
                                                     __HIP_MEMORY_SCOPE_AGENT);
                xs[h_dst] = __uint_as_float(u);
            }
            __syncthreads();
        }

        // compute own strip: sliding 3x3 window down 12 rows
        float acc[RPX];
        {
            const int base = (wv * RPX) * RXs + lane;
            float a0 = xs[base],       a1 = xs[base + 1],       a2 = xs[base + 2];
            float b0 = xs[base + RXs], b1 = xs[base + RXs + 1], b2 = xs[base + RXs + 2];
#pragma unroll
            for (int r = 0; r < RPX; ++r) {
                const int idx = base + (r + 2) * RXs;
                const float c0 = xs[idx], c1 = xs[idx + 1], c2 = xs[idx + 2];
                const float2 w01 = up2(wq[r].x);
                const float2 w23 = up2(wq[r].y);
                const float2 w45 = up2(wq[r].z);
                const float2 w67 = up2(wq[r].w);
                const float2 w8b = up2(wb[r]);
                float a = w8b.y;                     // bias
                a = fmaf(w01.x, a0, a); a = fmaf(w01.y, a1, a); a = fmaf(w23.x, a2, a);
                a = fmaf(w23.y, b0, a); a = fmaf(w45.x, b1, a); a = fmaf(w45.y, b2, a);
                a = fmaf(w67.x, c0, a); a = fmaf(w67.y, c1, a); a = fmaf(w8b.x, c2, a);
                acc[r] = a;
                a0 = b0; a1 = b1; a2 = b2;
                b0 = c0; b1 = c1; b2 = c2;
            }
        }
        __syncthreads();                 // all LDS reads of step t done

        // write own results to LDS interior
#pragma unroll
        for (int r = 0; r < RPX; ++r)
            xs[(1 + wv * RPX + r) * RXs + (lane + 1)] = acc[r];

        if (t < NSTEP) {
            // publish tile boundary (from registers) into this step's ring
            unsigned* ringme = &rings[((size_t)(t & 1) * NBLK + (size_t)blk) * RING_STRIDE];
            if (wv == 0) ring_st(&ringme[lane], acc[0]);            // tile row 0
            if (wv == 3) ring_st(&ringme[64 + lane], acc[RPX - 1]); // tile row 47
            if (lane == 0) {
#pragma unroll
                for (int r = 0; r < RPX; ++r) ring_st(&ringme[128 + wv * RPX + r], acc[r]);
            }
            if (lane == 63) {
#pragma unroll
                for (int r = 0; r < RPX; ++r) ring_st(&ringme[176 + wv * RPX + r], acc[r]);
            }
            __syncthreads();             // drains vmcnt: ring stores globally visible
            if (tid == 0) {
                __threadfence();
                __hip_atomic_store(&flags[blk], (unsigned)t, __ATOMIC_RELEASE,
                                   __HIP_MEMORY_SCOPE_AGENT);
            }
        } else {
            // final step: write own tile rows straight to output (coalesced)
#pragma unroll
            for (int r = 0; r < RPX; ++r)
                out[(size_t)b * HW + (size_t)(by0 + wv * RPX + r) * W + (bx0 + lane)] = acc[r];
        }
    }
}

extern "C" void kernel_launch(void* const* d_in, const int* in_sizes, int n_in,
                              void* d_out, int out_size, void* d_ws, size_t ws_size,
                              hipStream_t stream) {
    const float* guided = (const float*)d_in[0];
    const float* x      = (const float*)d_in[1];
    const float* sparse = (const float*)d_in[2];
    float* out = (float*)d_out;

    // ws: flags (NBLK u32, zeroed each launch) | rings (2*NBLK*RING_STRIDE u32)
    unsigned* flags = (unsigned*)d_ws;
    unsigned* rings = (unsigned*)((char*)d_ws + 4096);

    hipMemsetAsync(flags, 0, NBLK * sizeof(unsigned), stream);

    dim3 blk(256, 1, 1);
    dim3 grd(NBX, NBY, BATCH);   // 800 blocks, all co-resident at 4 blocks/CU
    prop_persistent<<<grd, blk, 0, stream>>>(guided, x, sparse, out, flags, rings);
}

// Round 4
// 171.372 us; speedup vs baseline: 6.6036x; 6.6036x over previous
//
#include <hip/hip_runtime.h>
#include <hip/hip_fp16.h>
#include <math.h>

#define BATCH 8
#define H 480
#define W 640
#define HW (H * W)
#define NPIX ((size_t)BATCH * HW)

// ---- prop geometry: 8 steps fused per launch, 2 launches total ----
#define S 8
#define TX 64                 // output tile width
#define TY 32                 // output tile height
#define RX (TX + 2 * S)       // 80 region cols
#define RY (TY + 2 * S)       // 48 region rows
#define NT 320                // threads per prop block (80 cols x 4 strips)
#define SR (RY / 4)           // 12 rows per strip

__device__ __forceinline__ unsigned pk2(float a, float b) {
    unsigned lo = __half_as_ushort(__float2half_rn(a));
    unsigned hi = __half_as_ushort(__float2half_rn(b));
    return lo | (hi << 16);
}
__device__ __forceinline__ float lo2f(unsigned u) {
    return __half2float(__ushort_as_half((unsigned short)(u & 0xffffu)));
}
__device__ __forceinline__ float hi2f(unsigned u) {
    return __half2float(__ushort_as_half((unsigned short)(u >> 16)));
}

// Fused softmax + mask fold; 4 px/thread, float4 in, packed fp16 out.
__global__ __launch_bounds__(256) void fuse_kernel(
    const float* __restrict__ guided,   // (B,9,H,W)
    const float* __restrict__ x,        // (B,1,H,W)
    const float* __restrict__ sparse,   // (B,1,H,W)
    uint4* __restrict__ wpack,          // per px: {w0..w7} fp16
    uint4* __restrict__ w9b4)           // per 4 px: {w8,bias} fp16 pairs
{
    const int j = blockIdx.x * 256 + threadIdx.x;     // quad index in image
    const int b = blockIdx.z;
    const size_t p4 = (size_t)b * HW + 4 * (size_t)j;
    const size_t gb = (size_t)b * 9 * HW + 4 * (size_t)j;

    float4 g[9];
#pragma unroll
    for (int k = 0; k < 9; ++k)
        g[k] = *(const float4*)(guided + gb + (size_t)k * HW);
    const float4 xq = *(const float4*)(x + p4);
    const float4 sq = *(const float4*)(sparse + p4);
    const float* xp = (const float*)&xq;
    const float* sp = (const float*)&sq;

    uint4 wb;
    unsigned* wbp = (unsigned*)&wb;
#pragma unroll
    for (int cc = 0; cc < 4; ++cc) {
        float w[9];
        float m = -INFINITY;
#pragma unroll
        for (int k = 0; k < 9; ++k) {
            w[k] = ((const float*)&g[k])[cc];
            m = fmaxf(m, w[k]);
        }
        float ssum = 0.0f;
#pragma unroll
        for (int k = 0; k < 9; ++k) { w[k] = __expf(w[k] - m); ssum += w[k]; }
        const float mask = (sp[cc] > 0.0f) ? 1.0f : 0.0f;
        const float scale = (1.0f - mask) / ssum;
        uint4 wp;
        wp.x = pk2(w[0] * scale, w[1] * scale);
        wp.y = pk2(w[2] * scale, w[3] * scale);
        wp.z = pk2(w[4] * scale, w[5] * scale);
        wp.w = pk2(w[6] * scale, w[7] * scale);
        wpack[p4 + cc] = wp;
        wbp[cc] = pk2(w[8] * scale, mask * xp[cc]);
    }
    w9b4[(size_t)b * (HW / 4) + j] = wb;
}

// Eight fused Jacobi steps over an 80x48 region -> 64x32 output tile.
// Thread layout: col c = tid%80, strip s = tid/80 (12 rows each).
// Weights for own strip pixels live in registers; x region in LDS; per step
// a 3-wide sliding window walks down the strip (~3 LDS reads per px).
__global__ __launch_bounds__(NT) void prop8_kernel(
    const float* __restrict__ xin,      // (B,H,W)
    const uint4* __restrict__ wpack,
    const unsigned* __restrict__ w9b,
    float* __restrict__ xout)           // (B,H,W)
{
    __shared__ float xs[RY * RX];

    const int tid = threadIdx.x;
    const int c = tid % RX;             // region col
    const int s = tid / RX;             // strip
    const int r0 = s * SR;              // first strip row
    const int bx0 = blockIdx.x * TX, by0 = blockIdx.y * TY;
    const int b = blockIdx.z;
    const size_t ob = (size_t)b * HW;

    // region x load (zeros outside image)
    for (int i = tid; i < RY * RX; i += NT) {
        const int r = i / RX, cc = i % RX;
        const int gy = by0 - S + r, gx = bx0 - S + cc;
        float v = 0.0f;
        if (gy >= 0 && gy < H && gx >= 0 && gx < W)
            v = xin[ob + (size_t)gy * W + gx];
        xs[i] = v;
    }

    // own-strip weights -> registers (zeros outside image)
    uint4 wq[SR];
    unsigned wbr[SR];
    {
        const int gx = bx0 - S + c;
        const bool xok = (gx >= 0) && (gx < W);
#pragma unroll
        for (int r = 0; r < SR; ++r) {
            const int gy = by0 - S + r0 + r;
            if (xok && gy >= 0 && gy < H) {
                const size_t q = ob + (size_t)gy * W + gx;
                wq[r] = wpack[q];
                wbr[r] = w9b[q];
            } else {
                wq[r] = make_uint4(0u, 0u, 0u, 0u);
                wbr[r] = 0u;
            }
        }
    }
    __syncthreads();

    const bool cval = (c >= 1) && (c <= RX - 2);
    const int rm1 = (s == 0) ? 0 : (r0 - 1);          // clamped window top

    for (int t = 1; t <= S; ++t) {
        float acc[SR];
        if (cval) {
            float a0 = xs[rm1 * RX + c - 1], a1 = xs[rm1 * RX + c], a2 = xs[rm1 * RX + c + 1];
            float b0 = xs[r0 * RX + c - 1],  b1 = xs[r0 * RX + c],  b2 = xs[r0 * RX + c + 1];
#pragma unroll
            for (int i = 0; i < SR; ++i) {
                const int rp1 = (r0 + i + 1 > RY - 1) ? (RY - 1) : (r0 + i + 1);
                const float c0 = xs[rp1 * RX + c - 1];
                const float c1 = xs[rp1 * RX + c];
                const float c2 = xs[rp1 * RX + c + 1];
                const unsigned u01 = wq[i].x, u23 = wq[i].y, u45 = wq[i].z, u67 = wq[i].w;
                const unsigned u8b = wbr[i];
                float a = hi2f(u8b);                   // bias
                a = fmaf(lo2f(u01), a0, a);
                a = fmaf(hi2f(u01), a1, a);
                a = fmaf(lo2f(u23), a2, a);
                a = fmaf(hi2f(u23), b0, a);
                a = fmaf(lo2f(u45), b1, a);
                a = fmaf(hi2f(u45), b2, a);
                a = fmaf(lo2f(u67), c0, a);
                a = fmaf(hi2f(u67), c1, a);
                a = fmaf(lo2f(u8b), c2, a);
                acc[i] = a;
                a0 = b0; a1 = b1; a2 = b2;
                b0 = c0; b1 = c1; b2 = c2;
            }
        }
        __syncthreads();                 // all reads of step t complete

        if (cval && c >= t && c < RX - t) {
#pragma unroll
            for (int i = 0; i < SR; ++i) {
                const int r = r0 + i;
                if (r >= t && r < RY - t) xs[r * RX + c] = acc[i];
            }
        }
        __syncthreads();                 // step-t values visible
    }

    // write 64x32 tile (region interior), coalesced
    for (int i = tid; i < TX * TY; i += NT) {
        const int r = i / TX, cc = i % TX;
        xout[ob + (size_t)(by0 + r) * W + (bx0 + cc)] = xs[(S + r) * RX + (S + cc)];
    }
}

extern "C" void kernel_launch(void* const* d_in, const int* in_sizes, int n_in,
                              void* d_out, int out_size, void* d_ws, size_t ws_size,
                              hipStream_t stream) {
    const float* guided = (const float*)d_in[0];
    const float* x      = (const float*)d_in[1];
    const float* sparse = (const float*)d_in[2];
    float* out = (float*)d_out;

    // ws layout: wpack (16 B/px) | w9b (4 B/px) | xA (4 B/px)
    uint4*    wpack = (uint4*)d_ws;
    unsigned* w9b   = (unsigned*)(wpack + NPIX);
    float*    xA    = (float*)(w9b + NPIX);

    {
        dim3 blk(256, 1, 1);
        dim3 grd(HW / 4 / 256, 1, BATCH);   // 300 x 1 x 8
        fuse_kernel<<<grd, blk, 0, stream>>>(guided, x, sparse, wpack, (uint4*)w9b);
    }
    {
        dim3 blk(NT, 1, 1);
        dim3 grd(W / TX, H / TY, BATCH);    // 10 x 15 x 8
        prop8_kernel<<<grd, blk, 0, stream>>>(x,  wpack, w9b, xA);
        prop8_kernel<<<grd, blk, 0, stream>>>(xA, wpack, w9b, out);
    }
}